// Round 4
// baseline (1477.376 us; speedup 1.0000x reference)
//
#include <hip/hip_runtime.h>
#include <stdint.h>

#define B_ 256
#define T_ 512
#define F_ 128
#define U_ 256
#define H_ 64
#define G4U (4 * U_)

typedef __attribute__((ext_vector_type(8))) short short8;
typedef __attribute__((ext_vector_type(4))) float f32x4;
typedef __attribute__((ext_vector_type(4))) uint32_t u32x4;
typedef unsigned long long ull;

// LDS-only barrier: NO vmcnt drain (publish/seq stores stay in flight).
#define BARRIER_LDS() asm volatile("s_waitcnt lgkmcnt(0)\ns_barrier" ::: "memory")

__device__ __forceinline__ uint16_t f2bf(float f) {
  uint32_t u = __builtin_bit_cast(uint32_t, f);
  u += 0x7fffu + ((u >> 16) & 1u);
  return (uint16_t)(u >> 16);
}
__device__ __forceinline__ float sigm(float z) {
  return 1.0f / (1.0f + __expf(-z));
}
__device__ __forceinline__ ull ald(const ull* p) {
  return __hip_atomic_load(p, __ATOMIC_RELAXED, __HIP_MEMORY_SCOPE_AGENT);
}

// ---------------------------------------------------------------------------
// Persistent LSTM kernel.
// Grid: 128 WGs x 256 threads. bg = blockIdx&15 (16 batch rows), ug =
// blockIdx>>4 (32 hidden units). Group {bg + 16*ug, ug=0..7} exchanges h
// through a TAGGED buffer: each 8B word = {2 x bf16 payload | step tag}.
// Consumers poll the data words directly (single round trip replaces
// drain -> signal -> poll -> load). Two-slot parity buffer; overwrite-safe
// by the data-dependency slack (producer is at most 2 steps ahead).
// ---------------------------------------------------------------------------
__global__ __launch_bounds__(256, 1) void lstm_kernel(
    const float* __restrict__ x, const float* __restrict__ kern,
    const float* __restrict__ rker, const float* __restrict__ bias,
    uint16_t* __restrict__ seq, ull* __restrict__ hbuf)
{
  const int tid  = threadIdx.x;
  const int lane = tid & 63;
  const int wv   = tid >> 6;
  const int bg   = blockIdx.x & 15;
  const int ug   = blockIdx.x >> 4;

  // A-fragment staging: [ktile][lane][8 bf16]; read = ds_read_b128 at lane*16.
  __shared__ __align__(16) uint16_t x_stage[4][64][8];   // 4 KB
  __shared__ __align__(16) uint16_t h_stage[8][64][8];   // 8 KB
  __shared__ __align__(16) float    z_stage[128][20];    // 10 KB

  // ---- preload weights into registers as B-fragments ----
  short8 wf[2][8];   // rec_kernel frags: [coltile][ktile] (K=256)
  short8 kf[2][4];   // kernel frags:     [coltile][ktile] (K=128)
  float  bias_r[2];
  #pragma unroll
  for (int i2 = 0; i2 < 2; ++i2) {
    const int ct   = wv * 2 + i2;
    const int cloc = ct * 16 + (lane & 15);                     // local col 0..127
    const int gcol = (cloc >> 5) * U_ + ug * 32 + (cloc & 31);  // i|f|g|o blocks
    bias_r[i2] = bias[gcol];
    #pragma unroll
    for (int kt = 0; kt < 8; ++kt) {
      short8 v;
      #pragma unroll
      for (int j = 0; j < 8; ++j) {
        const int k = kt * 32 + (lane >> 4) * 8 + j;
        v[j] = (short)f2bf(rker[(size_t)k * G4U + gcol]);
      }
      wf[i2][kt] = v;
    }
    #pragma unroll
    for (int kt = 0; kt < 4; ++kt) {
      short8 v;
      #pragma unroll
      for (int j = 0; j < 8; ++j) {
        const int k = kt * 32 + (lane >> 4) * 8 + j;
        v[j] = (short)f2bf(kern[(size_t)k * G4U + gcol]);
      }
      kf[i2][kt] = v;
    }
  }

  // ---- roles ----
  const int xrow = tid & 15;                                   // x-staging row
  const int xfb  = (tid >> 6) * 32 + ((tid >> 4) & 3) * 8;     // feature base
  const int gr  = tid & 15;                                    // gate row
  const int u0  = (tid >> 4) * 2;                              // gate unit pair (local)
  // exchange: thread owns h_stage entries e0=tid, e1=tid+256
  // entry e: kt=e>>6, l=e&63 -> row=l&15, unit base kt*32+(l>>4)*8
  const int erow = lane & 15;
  const int ec0  = (tid >> 6) * 16 + ((lane >> 4) & 3) * 4;    // ull chunk base (kt 0..3)
                                                               // e1 -> chunk +64

  float cst0 = 0.f, cst1 = 0.f;   // persistent cell state (fp32)

  // ---- stage x for t=0 ----
  float xp[8];
  {
    const float* p = x + ((size_t)(bg * 16 + xrow) * T_ + 0) * F_ + xfb;
    #pragma unroll
    for (int j = 0; j < 8; ++j) xp[j] = p[j];
    uint16_t* d = (uint16_t*)x_stage + tid * 8;
    #pragma unroll
    for (int j = 0; j < 8; ++j) d[j] = f2bf(xp[j]);
  }
  __syncthreads();

  for (int t = 0; t < T_; ++t) {
    // (a) z_x = bias + x_t @ kernel
    f32x4 acc0 = {bias_r[0], bias_r[0], bias_r[0], bias_r[0]};
    f32x4 acc1 = {bias_r[1], bias_r[1], bias_r[1], bias_r[1]};
    #pragma unroll
    for (int kt = 0; kt < 4; ++kt) {
      short8 a = *(const short8*)&x_stage[kt][lane][0];
      acc0 = __builtin_amdgcn_mfma_f32_16x16x32_bf16(a, kf[0][kt], acc0, 0, 0, 0);
      acc1 = __builtin_amdgcn_mfma_f32_16x16x32_bf16(a, kf[1][kt], acc1, 0, 0, 0);
    }
    // issue x loads for t+1 (consumed just before BAR_f)
    {
      const int tn = (t + 1 < T_) ? t + 1 : t;
      const float* p = x + ((size_t)(bg * 16 + xrow) * T_ + tn) * F_ + xfb;
      #pragma unroll
      for (int j = 0; j < 8; ++j) xp[j] = p[j];
    }
    if (t > 0) {
      // (b) tagged poll+exchange: slot (t-1)&1, expect tag == t
      const uint32_t expt = (uint32_t)t;
      const ull* sb = hbuf + (size_t)((t - 1) & 1) * (B_ * 128)
                           + (size_t)(bg * 16 + erow) * 128;
      const ull* pa = sb + ec0;        // entry e0 (kt 0..3)
      const ull* pb = sb + ec0 + 64;   // entry e1 (kt 4..7)
      ull v0, v1, v2, v3, w0, w1, w2, w3;
      for (;;) {
        v0 = ald(pa + 0); v1 = ald(pa + 1); v2 = ald(pa + 2); v3 = ald(pa + 3);
        w0 = ald(pb + 0); w1 = ald(pb + 1); w2 = ald(pb + 2); w3 = ald(pb + 3);
        uint32_t bad = ((uint32_t)(v0 >> 32) ^ expt) | ((uint32_t)(v1 >> 32) ^ expt)
                     | ((uint32_t)(v2 >> 32) ^ expt) | ((uint32_t)(v3 >> 32) ^ expt)
                     | ((uint32_t)(w0 >> 32) ^ expt) | ((uint32_t)(w1 >> 32) ^ expt)
                     | ((uint32_t)(w2 >> 32) ^ expt) | ((uint32_t)(w3 >> 32) ^ expt);
        if (bad == 0u) break;
      }
      u32x4* hs = (u32x4*)h_stage;
      hs[tid]       = (u32x4){(uint32_t)v0, (uint32_t)v1, (uint32_t)v2, (uint32_t)v3};
      hs[tid + 256] = (u32x4){(uint32_t)w0, (uint32_t)w1, (uint32_t)w2, (uint32_t)w3};
    }
    BARRIER_LDS();   // (d) h_stage ready (also orders t=0 x_stage read/write)
    if (t > 0) {
      // (e) z += h_{t-1} @ rec_kernel
      #pragma unroll
      for (int kt = 0; kt < 8; ++kt) {
        short8 a = *(const short8*)&h_stage[kt][lane][0];
        acc0 = __builtin_amdgcn_mfma_f32_16x16x32_bf16(a, wf[0][kt], acc0, 0, 0, 0);
        acc1 = __builtin_amdgcn_mfma_f32_16x16x32_bf16(a, wf[1][kt], acc1, 0, 0, 0);
      }
    }
    {
      const int c0 = (wv * 2 + 0) * 16 + (lane & 15);
      const int c1 = (wv * 2 + 1) * 16 + (lane & 15);
      const int r0 = (lane >> 4) * 4;
      *(f32x4*)&z_stage[c0][r0] = acc0;   // z_stage[col][row]
      *(f32x4*)&z_stage[c1][r0] = acc1;
      uint16_t* d = (uint16_t*)x_stage + tid * 8;   // stage x_{t+1}
      #pragma unroll
      for (int j = 0; j < 8; ++j) d[j] = f2bf(xp[j]);
    }
    BARRIER_LDS();   // (f) z_stage + x_stage ready
    // (g) gates + state update + tagged publish
    {
      const float zi0 = z_stage[u0][gr],      zi1 = z_stage[u0 + 1][gr];
      const float zf0 = z_stage[32 + u0][gr], zf1 = z_stage[33 + u0][gr];
      const float zg0 = z_stage[64 + u0][gr], zg1 = z_stage[65 + u0][gr];
      const float zo0 = z_stage[96 + u0][gr], zo1 = z_stage[97 + u0][gr];
      const float i0 = sigm(zi0), i1 = sigm(zi1);
      const float f0 = sigm(zf0), f1 = sigm(zf1);
      const float g0 = zg0 * sigm(zg0), g1 = zg1 * sigm(zg1);
      const float o0 = sigm(zo0), o1 = sigm(zo1);
      cst0 = f0 * cst0 + i0 * g0;
      cst1 = f1 * cst1 + i1 * g1;
      const float h0 = o0 * (cst0 * sigm(cst0));
      const float h1 = o1 * (cst1 * sigm(cst1));
      const uint32_t packed = (uint32_t)f2bf(h0) | ((uint32_t)f2bf(h1) << 16);
      // publish {payload|tag t+1} one-way; no drain needed before proceeding
      ull* wp = hbuf + (size_t)(t & 1) * (B_ * 128)
                     + (size_t)(bg * 16 + gr) * 128 + ((ug * 32 + u0) >> 1);
      __hip_atomic_store(wp, (ull)packed | ((ull)(uint32_t)(t + 1) << 32),
                         __ATOMIC_RELAXED, __HIP_MEMORY_SCOPE_AGENT);
      // seq store off the critical path
      *(uint32_t*)(seq + ((size_t)(bg * 16 + gr) * T_ + t) * U_ + ug * 32 + u0) = packed;
    }
  }
}

// ---------------------------------------------------------------------------
// Head GEMM: partials[g][b][h] = seq[b, g-chunk] @ w_out[g-chunk, h]
// ---------------------------------------------------------------------------
__global__ __launch_bounds__(256, 1) void head_kernel(
    const uint16_t* __restrict__ seq, const float* __restrict__ w_out,
    float* __restrict__ partials)
{
  const int g    = blockIdx.x;
  const int tid  = threadIdx.x;
  const int lane = tid & 63;
  const int wv   = tid >> 6;

  f32x4 acc[4][4];
  #pragma unroll
  for (int i = 0; i < 4; ++i)
    #pragma unroll
    for (int c = 0; c < 4; ++c) acc[i][c] = (f32x4){0.f, 0.f, 0.f, 0.f};

  for (int ks = 0; ks < 64; ++ks) {
    const int krow = g * 2048 + ks * 32 + (lane >> 4) * 8;
    short8 bf[4];
    #pragma unroll
    for (int c = 0; c < 4; ++c) {
      short8 v;
      #pragma unroll
      for (int j = 0; j < 8; ++j)
        v[j] = (short)f2bf(w_out[(size_t)(krow + j) * H_ + c * 16 + (lane & 15)]);
      bf[c] = v;
    }
    #pragma unroll
    for (int i = 0; i < 4; ++i) {
      const int b = (wv * 4 + i) * 16 + (lane & 15);
      short8 a = *(const short8*)(seq + (size_t)b * (T_ * U_) + krow);
      #pragma unroll
      for (int c = 0; c < 4; ++c)
        acc[i][c] = __builtin_amdgcn_mfma_f32_16x16x32_bf16(a, bf[c], acc[i][c], 0, 0, 0);
    }
  }
  #pragma unroll
  for (int i = 0; i < 4; ++i)
    #pragma unroll
    for (int c = 0; c < 4; ++c)
      #pragma unroll
      for (int r = 0; r < 4; ++r) {
        const int b = wv * 64 + i * 16 + (lane >> 4) * 4 + r;
        partials[((size_t)g * B_ + b) * H_ + c * 16 + (lane & 15)] = acc[i][c][r];
      }
}

__global__ void reduce_kernel(const float* __restrict__ partials,
                              const float* __restrict__ b_out,
                              float* __restrict__ out)
{
  const int i = blockIdx.x * 256 + threadIdx.x;   // b*64 + h
  float s = b_out[i & (H_ - 1)];
  #pragma unroll 8
  for (int g = 0; g < 64; ++g) s += partials[(size_t)g * (B_ * H_) + i];
  out[i] = s;
}

// ---------------------------------------------------------------------------
extern "C" void kernel_launch(void* const* d_in, const int* in_sizes, int n_in,
                              void* d_out, int out_size, void* d_ws, size_t ws_size,
                              hipStream_t stream) {
  (void)in_sizes; (void)n_in; (void)out_size; (void)ws_size;
  const float* x     = (const float*)d_in[0];
  const float* kern  = (const float*)d_in[1];
  const float* rker  = (const float*)d_in[2];
  const float* bias  = (const float*)d_in[3];
  const float* w_out = (const float*)d_in[4];
  const float* b_out = (const float*)d_in[5];
  float* out = (float*)d_out;

  char* ws = (char*)d_ws;
  const size_t seq_bytes  = (size_t)B_ * T_ * U_ * 2;          // 64 MB
  const size_t hbuf_bytes = (size_t)2 * B_ * 128 * 8;          // 512 KB tagged
  uint16_t* seq      = (uint16_t*)ws;
  ull*      hbuf     = (ull*)(ws + seq_bytes);
  float*    partials = (float*)(ws + seq_bytes + hbuf_bytes);  // 4 MB

  // per-launch re-init: stale tags from a previous replay could falsely
  // match (tags cycle 1..512) -> zero the tagged buffer every launch.
  hipMemsetAsync(hbuf, 0, hbuf_bytes, stream);

  lstm_kernel<<<128, 256, 0, stream>>>(x, kern, rker, bias, seq, hbuf);
  head_kernel<<<64, 256, 0, stream>>>(seq, w_out, partials);
  reduce_kernel<<<64, 256, 0, stream>>>(partials, b_out, out);
}